// Round 15
// baseline (164.913 us; speedup 1.0000x reference)
//
#include <hip/hip_runtime.h>
#include <math.h>

#define NUM_ENTITY 100000
#define NUM_TYPE   5000
#define DIM        128
#define BATCH      512
#define MARGIN     2.0f

#define TG 64       // types per block (one per lane)
#define BB 32       // batch rows per block (8 per wave)
#define BG 8        // batch rows per wave
#define TSTRIDE 68  // t-tile row stride in dwords (64+4; b128 row-reads = 2/bank = free)
#define REPS 8      // DIAGNOSTIC: repeat body to exceed the 42us harness fills
                    // so this kernel's rocprof counters appear in top-5.
                    // Idempotent (same stores every rep). Strip next round.

typedef _Float16 half_t;
typedef half_t half2_t __attribute__((ext_vector_type(2)));

// r14 falsified the "LDS-pipe broadcast" theory (removing inner-loop LDS
// didn't help) and the scalar-pipe path (no s_load from global). Waves are
// ~85% stalled vs VALU issue and counters have been invisible since r12.
// This round: (1) e-operand delivery via v_readlane — e rows live in lane
// VGPRs (coalesced 8B load/row/lane), inner loop broadcasts each dword with
// readlane (VALU pipe, no memory op, no latency). Inner loop = pure
// register compute. (2) REPS=8 instrumentation for counters.
__device__ __forceinline__ uint32_t pk2(float x, float y) {
    return __builtin_bit_cast(uint32_t, __builtin_amdgcn_cvt_pkrtz(x, y));
}

__device__ __forceinline__ float absdot(uint32_t eu, uint32_t tu, float acc) {
    const half2_t ones = {(half_t)1.0f, (half_t)1.0f};
    half2_t d = __builtin_bit_cast(half2_t, eu) - __builtin_bit_cast(half2_t, tu);
    const uint32_t du = __builtin_bit_cast(uint32_t, d) & 0x7fff7fffu;
#if __has_builtin(__builtin_amdgcn_fdot2)
    return __builtin_amdgcn_fdot2(__builtin_bit_cast(half2_t, du), ones, acc, false);
#else
    half2_t a = __builtin_bit_cast(half2_t, du);
    return acc + (float)a[0] + (float)a[1];
#endif
}

__global__ __launch_bounds__(256, 1) void l1dist_sigmoid_kernel(
    const float* __restrict__ ent,
    const float* __restrict__ typ,
    const int*   __restrict__ xb,
    float*       __restrict__ out)
{
    __shared__ uint32_t tL[TG * TSTRIDE];   // 17408 B, packed f16

    const int tid = threadIdx.x;            // 0..255
    const int l   = tid & 63;               // lane
    const int w   = tid >> 6;               // wave 0..3
    const int t0  = blockIdx.x * TG;
    const int b0  = blockIdx.y * BB;
    const int wb  = w * BG;                 // this wave's first b-row
    const bool valid = (t0 + l) < NUM_TYPE;

#pragma unroll 1
    for (int rep = 0; rep < REPS; ++rep) {
        __syncthreads();   // protect tL from previous rep's readers

        // ---- stage t tile COALESCED: 64 rows x 32 float4, 8 per thread
#pragma unroll
        for (int s = 0; s < 8; ++s) {
            const int g   = tid + 256 * s;
            const int row = g >> 5;
            const int c4  = g & 31;
            const int tr  = min(t0 + row, NUM_TYPE - 1);
            const float4 v = *(const float4*)&typ[tr * DIM + c4 * 4];
            uint2 pw;
            pw.x = pk2(v.x, v.y);
            pw.y = pk2(v.z, v.w);
            *(uint2*)&tL[row * TSTRIDE + c4 * 2] = pw;
        }

        // ---- e rows -> lane registers: lane l holds dims [2l,2l+1] of each
        // of this wave's 8 rows (coalesced 8B loads, one dword/row/lane)
        uint32_t ereg[BG];
#pragma unroll
        for (int i = 0; i < BG; ++i) {
            const int er = xb[b0 + wb + i];
            const float2 v = *(const float2*)&ent[er * DIM + 2 * l];
            ereg[i] = pk2(v.x, v.y);
        }

        __syncthreads();

        // ---- own type row LDS -> registers as 64 dwords (16 b128 reads)
        uint32_t tfd[64];
#pragma unroll
        for (int c = 0; c < 16; ++c) {
            const uint4 q = *(const uint4*)&tL[l * TSTRIDE + c * 4];
            tfd[4 * c + 0] = q.x;
            tfd[4 * c + 1] = q.y;
            tfd[4 * c + 2] = q.z;
            tfd[4 * c + 3] = q.w;
        }

        // ---- compute: pure-register inner loop; e broadcast via readlane
#pragma unroll
        for (int i = 0; i < BG; ++i) {
            float acc = 0.0f;
#pragma unroll
            for (int c = 0; c < 64; ++c) {
                const uint32_t es =
                    (uint32_t)__builtin_amdgcn_readlane((int)ereg[i], c);
                acc = absdot(es, tfd[c], acc);
            }
            if (valid) {
                const float x = MARGIN - acc;
                out[(b0 + wb + i) * NUM_TYPE + t0 + l] =
                    1.0f / (1.0f + __expf(-x));
            }
        }
    }
}

extern "C" void kernel_launch(void* const* d_in, const int* in_sizes, int n_in,
                              void* d_out, int out_size, void* d_ws, size_t ws_size,
                              hipStream_t stream) {
    const float* ent = (const float*)d_in[0];
    const float* typ = (const float*)d_in[1];
    const int*   xb  = (const int*)d_in[2];
    float*       out = (float*)d_out;

    dim3 grid((NUM_TYPE + TG - 1) / TG, BATCH / BB);  // (79, 16) = 1264 blocks x 4 waves
    dim3 block(256);
    l1dist_sigmoid_kernel<<<grid, block, 0, stream>>>(ent, typ, xb, out);
}